// Round 5
// baseline (537.472 us; speedup 1.0000x reference)
//
#include <hip/hip_runtime.h>
#include <hip/hip_bf16.h>

typedef __bf16 bf16_t;
typedef __bf16 bf16x8 __attribute__((ext_vector_type(8)));
typedef __bf16 bf16x4 __attribute__((ext_vector_type(4)));
typedef float  f32x4  __attribute__((ext_vector_type(4)));

static __device__ __forceinline__ f32x4 mfma16(bf16x8 a, bf16x8 b, f32x4 c) {
    return __builtin_amdgcn_mfma_f32_16x16x32_bf16(a, b, c, 0, 0, 0);
}

// ---------------------------------------------------------------------------
// Pack W1 edge rows [128..160) and W2 [256x256] into bf16 MFMA fragment order:
// frag[(tile16)*64 + lane][j] = W[8*(lane>>4)+j + 32*kstep][ct*16 + (lane&15)]
// ---------------------------------------------------------------------------
__global__ void prep_pack(const float* __restrict__ W1, const float* __restrict__ W2,
                          bf16_t* __restrict__ W1ef, bf16_t* __restrict__ W2f) {
    int t = blockIdx.x * blockDim.x + threadIdx.x;
    int l = t & 63;
    int g = l >> 4;
    int c = l & 15;
    if (t < 1024) {                       // W1 edge part
        int ct = t >> 6;
        #pragma unroll
        for (int j = 0; j < 8; ++j)
            W1ef[t * 8 + j] = (bf16_t)W1[(128 + 8 * g + j) * 256 + ct * 16 + c];
    } else if (t < 1024 + 8192) {         // W2
        int t2 = t - 1024;
        int ks = t2 >> 10;
        int ct = (t2 >> 6) & 15;
        #pragma unroll
        for (int j = 0; j < 8; ++j)
            W2f[t2 * 8 + j] = (bf16_t)W2[(ks * 32 + 8 * g + j) * 256 + ct * 16 + c];
    }
}

// ---------------------------------------------------------------------------
// Pi[b,i,h] = nodes[b,i,:] @ W1[0:128,h] + b1[h]   (f32)
// Pj[b,j,h] = nodes[b,j,:] @ W1[160:288,h]         (f32, temp)
// ---------------------------------------------------------------------------
__global__ __launch_bounds__(256) void prep_pij(const float* __restrict__ nodes,
                                                const float* __restrict__ W1,
                                                const float* __restrict__ b1,
                                                float* __restrict__ Pi,
                                                float* __restrict__ Pj) {
    int b = blockIdx.x >> 2;
    int q = blockIdx.x & 3;
    int h = threadIdx.x;
    const float* nb = nodes + (b * 64 + q * 16) * 128;
    float ai[16], aj[16];
    float bias = b1[h];
    #pragma unroll
    for (int ii = 0; ii < 16; ++ii) { ai[ii] = bias; aj[ii] = 0.f; }
    for (int d = 0; d < 128; ++d) {
        float wi = W1[d * 256 + h];
        float wj = W1[(160 + d) * 256 + h];
        #pragma unroll
        for (int ii = 0; ii < 16; ++ii) {
            float s = nb[ii * 128 + d];
            ai[ii] = fmaf(s, wi, ai[ii]);
            aj[ii] = fmaf(s, wj, aj[ii]);
        }
    }
    #pragma unroll
    for (int ii = 0; ii < 16; ++ii) {
        Pi[(b * 64 + q * 16 + ii) * 256 + h] = ai[ii];
        Pj[(b * 64 + q * 16 + ii) * 256 + h] = aj[ii];
    }
}

// ---------------------------------------------------------------------------
// Repack Pj f32 -> Pjf bf16 fragment-linear per batch (verified layout, R2-R4).
// unit U(j,h) = ((j>>4)*8 + (h>>5))*64 + ((h>>3)&3)*16 + (j&15); elem e = h&7
// ---------------------------------------------------------------------------
__global__ __launch_bounds__(256) void prep_pjf(const float* __restrict__ Pj,
                                                bf16_t* __restrict__ Pjf) {
    int u = blockIdx.x * 256 + threadIdx.x;
    int b = u >> 11, u2 = u & 2047;
    int pt = u2 >> 9, ks = (u2 >> 6) & 7, q = (u2 >> 4) & 3, c = u2 & 15;
    int j = pt * 16 + c, h0 = ks * 32 + q * 8;
    const float* src = Pj + ((long)(b * 64 + j)) * 256 + h0;
    f32x4 v0 = *(const f32x4*)src;
    f32x4 v1 = *(const f32x4*)(src + 4);
    bf16x8 o;
    #pragma unroll
    for (int e = 0; e < 4; ++e) { o[e] = (bf16_t)v0[e]; o[4 + e] = (bf16_t)v1[e]; }
    *(bf16x8*)(Pjf + (long)u * 8) = o;
}

// ---------------------------------------------------------------------------
// Persistent fused MLP v5. 512 blocks x 512 thr (2 blocks/CU), 8 batches of
// 128 pairs each. Wave (ph = pair-half, hq = h-quarter). Edges staged to LDS
// as bf16 once per batch (issue-early/write-late). W2f streamed from L2$ once
// per batch. Fragment-linear a1f (R2-R4 verified layout).
// ---------------------------------------------------------------------------
__global__ __launch_bounds__(512, 4) void mlp_main(
    const float* __restrict__ edges,
    const float* __restrict__ Pi, const bf16_t* __restrict__ Pjf,
    const bf16_t* __restrict__ W1ef, const bf16_t* __restrict__ W2f,
    const float* __restrict__ b2, const float* __restrict__ W3,
    const float* __restrict__ b3, float* __restrict__ out) {

    __shared__ bf16_t a1f[32768];         // 64 KB: 8 pair-tiles x 8 ks x 64 x 16B
    __shared__ bf16_t elds[4096];         // 8 KB: 128 pairs x 32 bf16
    __shared__ float part[4][128];        // 2 KB

    const int p = blockIdx.x;
    const int xb = (p & 7) * 64 + (p >> 3);    // XCD swizzle (512 % 8 == 0)
    const int b = xb >> 2;
    const int tid = threadIdx.x;
    const int w = tid >> 6, l = tid & 63, g = l >> 4, c = l & 15;
    const int ph = w >> 2, hq = w & 3;

    const long blockPairBase = (long)xb * 1024;  // 8 batches x 128 pairs

    // W1e fragments for this wave's h-quarter (16 VGPR)
    bf16x8 wf[4];
    #pragma unroll
    for (int ht = 0; ht < 4; ++ht)
        wf[ht] = *(const bf16x8*)&W1ef[((hq * 4 + ht) * 64 + l) * 8];

    const float bias3 = b3[0];
    const bf16_t* PjB = Pjf + (long)b * 16384;

    // ---- prologue: stage batch 0 edges (f32 -> bf16 -> LDS) ----
    f32x4 ea, eb;
    {
        const float* ep = edges + (blockPairBase + (tid >> 2)) * 32 + (tid & 3) * 8;
        ea = *(const f32x4*)ep;
        eb = *(const f32x4*)(ep + 4);
        bf16x8 ev;
        #pragma unroll
        for (int j = 0; j < 4; ++j) { ev[j] = (bf16_t)ea[j]; ev[4 + j] = (bf16_t)eb[j]; }
        *(bf16x8*)&elds[tid * 8] = ev;
    }
    __syncthreads();

    for (int bt = 0; bt < 8; ++bt) {
        // ---------------- layer 1: h-quarter x pair-half ----------------
        {
            const f32x4 z4 = {0.f, 0.f, 0.f, 0.f};
            f32x4 acc1[4][4];             // [ht][pt]
            #pragma unroll
            for (int ht = 0; ht < 4; ++ht)
                #pragma unroll
                for (int pt = 0; pt < 4; ++pt) acc1[ht][pt] = z4;
            bf16x8 ef[4];
            #pragma unroll
            for (int pt = 0; pt < 4; ++pt)
                ef[pt] = *(const bf16x8*)&elds[(ph * 64 + pt * 16 + c) * 32 + g * 8];
            #pragma unroll
            for (int pt = 0; pt < 4; ++pt)
                #pragma unroll
                for (int ht = 0; ht < 4; ++ht)
                    acc1[ht][pt] = mfma16(wf[ht], ef[pt], acc1[ht][pt]);

            // epilogue: +Pi +Pj, relu, bf16x4 -> a1f (fragment-linear)
            const int i_ = (xb & 3) * 16 + bt * 2 + ph;
            const float* PiB = Pi + ((long)b * 64 + i_) * 256 + hq * 64;
            #pragma unroll
            for (int ht = 0; ht < 4; ++ht) {
                f32x4 piv = *(const f32x4*)(PiB + ht * 16 + 4 * g);
                const int rowsel = 2 * (ht & 1) + (g >> 1);
                #pragma unroll
                for (int pt = 0; pt < 4; ++pt) {
                    int offj = ((pt * 8 + hq * 2 + (ht >> 1)) * 64 + rowsel * 16 + c) * 8
                               + 4 * (g & 1);
                    bf16x4 pj = *(const bf16x4*)(PjB + offj);
                    int offa = (((ph * 4 + pt) * 8 + hq * 2 + (ht >> 1)) * 64
                                + rowsel * 16 + c) * 8 + 4 * (g & 1);
                    bf16x4 o;
                    #pragma unroll
                    for (int r = 0; r < 4; ++r) {
                        float v = acc1[ht][pt][r] + piv[r] + (float)pj[r];
                        v = v > 0.f ? v : 0.f;
                        o[r] = (bf16_t)v;
                    }
                    *(bf16x4*)&a1f[offa] = o;
                }
            }
        }
        __syncthreads();                  // bar1: a1f ready, elds consumed

        // issue next batch's edge loads (land during the L2 phase)
        if (bt < 7) {
            const float* ep = edges
                + (blockPairBase + (bt + 1) * 128 + (tid >> 2)) * 32 + (tid & 3) * 8;
            ea = *(const f32x4*)ep;
            eb = *(const f32x4*)(ep + 4);
        }

        // ---------------- layer 2 + layer 3 ----------------
        {
            const f32x4 z4 = {0.f, 0.f, 0.f, 0.f};
            f32x4 acc2[4][4];             // [pt][ct]
            #pragma unroll
            for (int pt = 0; pt < 4; ++pt)
                #pragma unroll
                for (int ct = 0; ct < 4; ++ct) acc2[pt][ct] = z4;
            #pragma unroll
            for (int ks = 0; ks < 8; ++ks) {
                bf16x8 af[4];
                #pragma unroll
                for (int pt = 0; pt < 4; ++pt)
                    af[pt] = *(const bf16x8*)&a1f[(((ph * 4 + pt) * 8 + ks) * 64 + l) * 8];
                #pragma unroll
                for (int ct = 0; ct < 4; ++ct) {
                    bf16x8 w2 = *(const bf16x8*)&W2f[((ks * 16 + hq * 4 + ct) * 64 + l) * 8];
                    #pragma unroll
                    for (int pt = 0; pt < 4; ++pt)
                        acc2[pt][ct] = mfma16(w2, af[pt], acc2[pt][ct]);
                }
            }

            // layer 3: relu(a2+b2) . W3 over this wave's h-quarter
            f32x4 b2q[4], w3q[4];
            #pragma unroll
            for (int ct = 0; ct < 4; ++ct) {
                b2q[ct] = *(const f32x4*)&b2[hq * 64 + ct * 16 + 4 * g];
                w3q[ct] = *(const f32x4*)&W3[hq * 64 + ct * 16 + 4 * g];
            }
            #pragma unroll
            for (int pt = 0; pt < 4; ++pt) {
                float s = 0.f;
                #pragma unroll
                for (int ct = 0; ct < 4; ++ct)
                    #pragma unroll
                    for (int r = 0; r < 4; ++r) {
                        float v = acc2[pt][ct][r] + b2q[ct][r];
                        v = v > 0.f ? v : 0.f;
                        s = fmaf(v, w3q[ct][r], s);
                    }
                s += __shfl_xor(s, 16);   // reduce over g
                s += __shfl_xor(s, 32);
                if (g == 0) part[hq][ph * 64 + pt * 16 + c] = s;
            }
        }

        // write staged edges for next batch (loads have had the whole L2 phase)
        if (bt < 7) {
            bf16x8 ev;
            #pragma unroll
            for (int j = 0; j < 4; ++j) { ev[j] = (bf16_t)ea[j]; ev[4 + j] = (bf16_t)eb[j]; }
            *(bf16x8*)&elds[tid * 8] = ev;
        }
        __syncthreads();                  // bar2: part + staged edges ready

        if (tid < 128) {
            float s = bias3 + part[0][tid] + part[1][tid] + part[2][tid] + part[3][tid];
            out[blockPairBase + bt * 128 + tid] = s;
        }
    }
}

extern "C" void kernel_launch(void* const* d_in, const int* in_sizes, int n_in,
                              void* d_out, int out_size, void* d_ws, size_t ws_size,
                              hipStream_t stream) {
    const float* nodes = (const float*)d_in[0];
    const float* edges = (const float*)d_in[1];
    const float* W1    = (const float*)d_in[2];
    const float* b1    = (const float*)d_in[3];
    const float* W2    = (const float*)d_in[4];
    const float* b2    = (const float*)d_in[5];
    const float* W3    = (const float*)d_in[6];
    const float* b3    = (const float*)d_in[7];
    float* out = (float*)d_out;

    char* ws = (char*)d_ws;
    float*  Pi   = (float*)ws;                                        // 8 MB
    float*  Pj   = (float*)(ws + (size_t)8 * 1024 * 1024);            // 8 MB (temp)
    bf16_t* Pjf  = (bf16_t*)(ws + (size_t)16 * 1024 * 1024);          // 4 MB
    bf16_t* W2f  = (bf16_t*)(ws + (size_t)20 * 1024 * 1024);          // 128 KB
    bf16_t* W1ef = (bf16_t*)(ws + (size_t)20 * 1024 * 1024 + 131072); // 16 KB

    prep_pack<<<dim3(36), dim3(256), 0, stream>>>(W1, W2, W1ef, W2f);
    prep_pij<<<dim3(512), dim3(256), 0, stream>>>(nodes, W1, b1, Pi, Pj);
    prep_pjf<<<dim3(1024), dim3(256), 0, stream>>>(Pj, Pjf);
    mlp_main<<<dim3(512), dim3(512), 0, stream>>>(edges, Pi, Pjf, W1ef, W2f, b2, W3, b3, out);
}